// Round 10
// baseline (1149.789 us; speedup 1.0000x reference)
//
#include <hip/hip_runtime.h>

// Problem constants (fixed by the reference)
#define N_TOKENS 32768
#define N_CODES  8192
#define DIM      512

// GEMM tiling (round-0-proven 128x128, BK=64, 2 blocks/CU)
#define BMT 128
#define BNT 128
#define SLICES 4
#define SLICE_CODES (N_CODES / SLICES)   // 2048
#define NTILES (SLICE_CODES / BNT)       // 16
#define BK 64
#define CHUNKS (DIM / BK)                // 8

#define CAP_FLAG 32768                   // fallback capacity = ALL tokens: overflow impossible
#define SLACK 0.25f                      // covers MFMA accum / fp32 rounding (~1e-3, big margin)

// Output layout (FP32 elements, reference return order)
#define OUT_VQ     16777216
#define OUT_COMMIT 16777217
#define OUT_IDX    16777218

// Workspace byte offsets (identical envelope to rounds 0-9: 85,983,232)
#define WS_CBHI   0                      //  8 MB codebook f16 hi
#define WS_CBLO   8388608                //  8 MB codebook f16 lo
#define WS_NC     16777216               // 32 KB exact fp32 code norms
#define WS_NORMZ  16809984               // 256 KB per-token (|zh|^2, |zl|^2)
#define WS_MISC   17072128               // 16 B: [0] max|cl|^2 [1] max|ch|^2 [2] flagcnt [3] accum
#define WS_LIST   17072144               // 128 KB flagged-token list (32768 ints, ends 17203216)
#define WS_PART   17301504               // 1.5 MB Part[32768][4] (12B each, ends 18874368)
                                         //   region reused as 1MB float2 fpart by exact path
#define WS_ZEHI   18874368               // 32 MB z_e f16 hi
#define WS_ZELO   52428800               // 32 MB z_e f16 lo (ends 85983232)
#define WS_NEED_FAST 85983232

typedef _Float16 f16x8 __attribute__((ext_vector_type(8)));
typedef _Float16 f16x4 __attribute__((ext_vector_type(4)));
typedef float    f32x4 __attribute__((ext_vector_type(4)));

// Per-(token, slice) summary: top-3 values, top-2 indices (slice-local).
// v2 = v1 + f16(dd&0xffff), v3 = v1 + f16(dd>>16); deltas FLOOR-rounded so
// reconstructed v2',v3' <= true v2,v3 (certification strictly conservative).
struct Part { float v1; unsigned int ii; unsigned int dd; };   // 12 B

// floor-rounding float -> f16 bits (x >= 0)
__device__ __forceinline__ unsigned short h_floor(float x) {
    union { _Float16 h; unsigned short b; } u;
    u.h = (_Float16)x;                       // nearest
    if ((float)u.h > x && u.b) --u.b;        // positive halfs: bits-- = next smaller
    return u.b;
}
__device__ __forceinline__ float h_unpack(unsigned int b) {
    union { unsigned short b; _Float16 h; } u;
    u.b = (unsigned short)b;
    return (float)u.h;
}

// XOR-swizzled LDS half-index for (row, kgrp of 8 halves); row stride 128B.
// Conflict-clean (verified rounds 0-9).
__device__ __forceinline__ int sw_idx(int row, int kgrp) {
    return row * 64 + ((kgrp ^ (row & 7)) << 3);
}

// async 16B global->LDS (lds dest = wave-uniform base + lane*16; global src per-lane)
__device__ __forceinline__ void async_copy16(void* lds, const void* g) {
    __builtin_amdgcn_global_load_lds(
        (const __attribute__((address_space(1))) unsigned int*)g,
        (__attribute__((address_space(3))) unsigned int*)lds,
        16, 0, 0);
}

// ---------------------------------------------------------------------------
// Kernel 0: zero misc block (max norms, flag count, loss accum)
__global__ void vq_init_kernel(unsigned int* misc) {
    if (threadIdx.x < 4) misc[threadIdx.x] = 0u;
}

// ---------------------------------------------------------------------------
// Kernel 1a: codebook -> f16 hi/lo planes + exact norms + global max split-norms.
__global__ void vq_prep_cb_kernel(const float* __restrict__ cb,
                                  _Float16* __restrict__ cb_hi,
                                  _Float16* __restrict__ cb_lo,
                                  float* __restrict__ nc,
                                  unsigned int* __restrict__ misc) {
    const int wid  = threadIdx.x >> 6;
    const int lane = threadIdx.x & 63;
    const int row  = blockIdx.x * 4 + wid;
    const float4* src = (const float4*)(cb + (size_t)row * DIM);
    float4 v0 = src[lane * 2];
    float4 v1 = src[lane * 2 + 1];
    float s = v0.x*v0.x + v0.y*v0.y + v0.z*v0.z + v0.w*v0.w
            + v1.x*v1.x + v1.y*v1.y + v1.z*v1.z + v1.w*v1.w;
    f16x8 hi = {(_Float16)v0.x, (_Float16)v0.y, (_Float16)v0.z, (_Float16)v0.w,
                (_Float16)v1.x, (_Float16)v1.y, (_Float16)v1.z, (_Float16)v1.w};
    float h0=(float)hi[0], h1=(float)hi[1], h2=(float)hi[2], h3=(float)hi[3];
    float h4=(float)hi[4], h5=(float)hi[5], h6=(float)hi[6], h7=(float)hi[7];
    float l0=v0.x-h0, l1=v0.y-h1, l2=v0.z-h2, l3=v0.w-h3;
    float l4=v1.x-h4, l5=v1.y-h5, l6=v1.z-h6, l7=v1.w-h7;
    f16x8 lo = {(_Float16)l0,(_Float16)l1,(_Float16)l2,(_Float16)l3,
                (_Float16)l4,(_Float16)l5,(_Float16)l6,(_Float16)l7};
    *(f16x8*)&cb_hi[(size_t)row * DIM + lane * 8] = hi;
    *(f16x8*)&cb_lo[(size_t)row * DIM + lane * 8] = lo;
    float sh = h0*h0+h1*h1+h2*h2+h3*h3+h4*h4+h5*h5+h6*h6+h7*h7;
    float sl = l0*l0+l1*l1+l2*l2+l3*l3+l4*l4+l5*l5+l6*l6+l7*l7;
#pragma unroll
    for (int off = 32; off > 0; off >>= 1) {
        s  += __shfl_down(s, off);
        sh += __shfl_down(sh, off);
        sl += __shfl_down(sl, off);
    }
    if (lane == 0) {
        nc[row] = s;
        atomicMax(&misc[0], __float_as_uint(sl));  // max ||c_lo||^2
        atomicMax(&misc[1], __float_as_uint(sh));  // max ||c_hi||^2
    }
}

// Kernel 1b: z_e -> f16 hi/lo planes + per-token split norms (fast path only).
__global__ void vq_prep_ze_kernel(const float* __restrict__ z_e,
                                  _Float16* __restrict__ ze_hi,
                                  _Float16* __restrict__ ze_lo,
                                  float2* __restrict__ normz) {
    const int wid  = threadIdx.x >> 6;
    const int lane = threadIdx.x & 63;
    const int row  = blockIdx.x * 4 + wid;
    const float4* src = (const float4*)(z_e + (size_t)row * DIM);
    float4 v0 = src[lane * 2];
    float4 v1 = src[lane * 2 + 1];
    f16x8 hi = {(_Float16)v0.x, (_Float16)v0.y, (_Float16)v0.z, (_Float16)v0.w,
                (_Float16)v1.x, (_Float16)v1.y, (_Float16)v1.z, (_Float16)v1.w};
    float h0=(float)hi[0], h1=(float)hi[1], h2=(float)hi[2], h3=(float)hi[3];
    float h4=(float)hi[4], h5=(float)hi[5], h6=(float)hi[6], h7=(float)hi[7];
    float l0=v0.x-h0, l1=v0.y-h1, l2=v0.z-h2, l3=v0.w-h3;
    float l4=v1.x-h4, l5=v1.y-h5, l6=v1.z-h6, l7=v1.w-h7;
    f16x8 lo = {(_Float16)l0,(_Float16)l1,(_Float16)l2,(_Float16)l3,
                (_Float16)l4,(_Float16)l5,(_Float16)l6,(_Float16)l7};
    *(f16x8*)&ze_hi[(size_t)row * DIM + lane * 8] = hi;
    *(f16x8*)&ze_lo[(size_t)row * DIM + lane * 8] = lo;
    float sh = h0*h0+h1*h1+h2*h2+h3*h3+h4*h4+h5*h5+h6*h6+h7*h7;
    float sl = l0*l0+l1*l1+l2*l2+l3*l3+l4*l4+l5*l5+l6*l6+l7*l7;
#pragma unroll
    for (int off = 32; off > 0; off >>= 1) {
        sh += __shfl_down(sh, off);
        sl += __shfl_down(sl, off);
    }
    if (lane == 0) normz[row] = make_float2(sh, sl);
}

// ---------------------------------------------------------------------------
// Kernel 2: 1-pass hi*hi GEMM + per-slice TOP-3 values / TOP-2 indices.
// r0-proven GEMM structure (proven again in r9 at 393us). Epilogue upgraded:
// top-3 tracking cuts the flag rate from ~20% (top-2 cert, r9) to ~2%
// (cert on the 3rd-best value; 2nd-best index is now a refine candidate).
__global__ __launch_bounds__(256, 2)
void vq_main_hi_kernel(const _Float16* __restrict__ ze_hi,
                       const _Float16* __restrict__ cb_hi,
                       const float* __restrict__ nc,
                       Part* __restrict__ parts) {
    // GEMM: 32KB (As 16KB + Bs 16KB). Epilogue reduction: 40KB (5 arrays x 8KB).
    __shared__ __align__(16) unsigned char smem[49152];
    _Float16* As = (_Float16*)smem;           // [128][64] halves
    _Float16* Bs = (_Float16*)smem + 8192;

    const int tid    = threadIdx.x;
    const int wid    = tid >> 6;
    const int lane   = tid & 63;
    const int wave_m = wid >> 1;
    const int wave_n = wid & 1;
    const int lane15 = lane & 15;
    const int quad   = lane >> 4;

    const int ns   = blockIdx.y;
    const int row0 = blockIdx.x * BMT;
    const int c00  = ns * SLICE_CODES;

    // per-slot top-3 values + top-2 indices
    float tv1[4][4], tv2[4][4], tv3[4][4];
    int   ti1[4][4], ti2[4][4];
#pragma unroll
    for (int mi = 0; mi < 4; ++mi)
#pragma unroll
        for (int r = 0; r < 4; ++r) {
            tv1[mi][r] = __builtin_inff(); tv2[mi][r] = __builtin_inff();
            tv3[mi][r] = __builtin_inff();
            ti1[mi][r] = c00; ti2[mi][r] = c00;
        }

    const int b_r8 = lane >> 3;
    const int b_g  = lane & 7;

#pragma unroll 1
    for (int nt = 0; nt < NTILES; ++nt) {
        const int c0 = c00 + nt * BNT;
        f32x4 acc[4][4];
#pragma unroll
        for (int mi = 0; mi < 4; ++mi)
#pragma unroll
            for (int ni = 0; ni < 4; ++ni) acc[mi][ni] = (f32x4){0.f, 0.f, 0.f, 0.f};

#pragma unroll 1
        for (int kc = 0; kc < CHUNKS; ++kc) {
            __syncthreads();
#pragma unroll
            for (int i = 0; i < 4; ++i) {
                const int L = wid * 4 + i;
                const int row = L * 8 + b_r8;
                const int g = (b_g ^ (row & 7)) << 3;
                async_copy16(Bs + L * 512, cb_hi + (size_t)(c0 + row) * DIM + kc * BK + g);
                async_copy16(As + L * 512, ze_hi + (size_t)(row0 + row) * DIM + kc * BK + g);
            }
            __syncthreads();

#pragma unroll
            for (int ks = 0; ks < 2; ++ks) {
                const int kg = ks * 4 + quad;
                f16x8 ah[4], bh[4];
#pragma unroll
                for (int mi = 0; mi < 4; ++mi)
                    ah[mi] = *(const f16x8*)&As[sw_idx(wave_m * 64 + mi * 16 + lane15, kg)];
#pragma unroll
                for (int ni = 0; ni < 4; ++ni)
                    bh[ni] = *(const f16x8*)&Bs[sw_idx(wave_n * 64 + ni * 16 + lane15, kg)];
#pragma unroll
                for (int mi = 0; mi < 4; ++mi)
#pragma unroll
                    for (int ni = 0; ni < 4; ++ni)
                        acc[mi][ni] = __builtin_amdgcn_mfma_f32_16x16x32_f16(
                            ah[mi], bh[ni], acc[mi][ni], 0, 0, 0);
            }
        }

        // top-3 update
#pragma unroll
        for (int ni = 0; ni < 4; ++ni) {
            const int c = c0 + wave_n * 64 + ni * 16 + lane15;
            const float nrm = nc[c];
#pragma unroll
            for (int mi = 0; mi < 4; ++mi)
#pragma unroll
                for (int r = 0; r < 4; ++r) {
                    const float v = fmaf(-2.0f, acc[mi][ni][r], nrm);
                    if (v < tv1[mi][r]) {
                        tv3[mi][r] = tv2[mi][r];
                        tv2[mi][r] = tv1[mi][r]; ti2[mi][r] = ti1[mi][r];
                        tv1[mi][r] = v;          ti1[mi][r] = c;
                    } else if (v < tv2[mi][r]) {
                        tv3[mi][r] = tv2[mi][r];
                        tv2[mi][r] = v;          ti2[mi][r] = c;
                    } else if (v < tv3[mi][r]) {
                        tv3[mi][r] = v;
                    }
                }
        }
    }

    // block top-3 reduction, two row-halves (40KB LDS): [2 wave_n][64 rows][16]
    float* rv1 = (float*)smem;
    float* rv2 = rv1 + 2048;
    float* rv3 = rv2 + 2048;
    int*   ri1 = (int*)(rv3 + 2048);
    int*   ri2 = ri1 + 2048;

#pragma unroll 1
    for (int half = 0; half < 2; ++half) {
        __syncthreads();   // also protects GEMM smem reuse on first iteration
        if (wave_m == half) {
#pragma unroll
            for (int mi = 0; mi < 4; ++mi)
#pragma unroll
                for (int r = 0; r < 4; ++r) {
                    const int rl = mi * 16 + quad * 4 + r;          // row within half
                    const int o  = wave_n * 1024 + rl * 16 + lane15;
                    rv1[o] = tv1[mi][r]; rv2[o] = tv2[mi][r]; rv3[o] = tv3[mi][r];
                    ri1[o] = ti1[mi][r]; ri2[o] = ti2[mi][r];
                }
        }
        __syncthreads();
        if (tid < 64) {
            float v1 = __builtin_inff(), v2 = __builtin_inff(), v3 = __builtin_inff();
            int   i1 = c00, i2 = c00;
            auto ins = [&](float v, int i) {
                if (v < v1) { v3 = v2; v2 = v1; i2 = i1; v1 = v; i1 = i; }
                else if (v < v2) { v3 = v2; v2 = v; i2 = i; }
                else if (v < v3) { v3 = v; }
            };
            for (int j = 0; j < 32; ++j) {
                const int o = (j >= 16 ? 1024 : 0) + tid * 16 + (j & 15);
                ins(rv1[o], ri1[o]);
                ins(rv2[o], ri2[o]);
                ins(rv3[o], c00);   // a3 provably never reaches top-2 of the union
            }
            Part P;
            P.v1 = v1;
            P.ii = (unsigned int)(i1 - c00) | ((unsigned int)(i2 - c00) << 16);
            P.dd = (unsigned int)h_floor(v2 - v1) | ((unsigned int)h_floor(v3 - v1) << 16);
            parts[(size_t)(row0 + half * 64 + tid) * SLICES + ns] = P;
        }
    }
}

// ---------------------------------------------------------------------------
// Kernel 3: certify + refine merge.
// Any code c with s_hi(c) > g1 + 2B cannot be the true argmin (|s-s_hi| <= B).
// cert: every slice's v3' > thresh  =>  all codes beyond the stored top-2 are
// excluded; refine {i1,i2 : value <= thresh} with exact fp32 dots. Else flag.
__global__ void vq_merge_cert_kernel(const float* __restrict__ z_e,
                                     const float* __restrict__ cb,
                                     const float* __restrict__ nc,
                                     const Part* __restrict__ parts,
                                     const float2* __restrict__ normz,
                                     unsigned int* __restrict__ misc,
                                     int* __restrict__ list,
                                     float* __restrict__ out,
                                     float* __restrict__ accum) {
    __shared__ float wpart[4];
    const int wid  = threadIdx.x >> 6;
    const int lane = threadIdx.x & 63;
    const int tbase = blockIdx.x * 64 + wid * 16;
    const float maxCl = sqrtf(__uint_as_float(misc[0]));
    const float maxCh = sqrtf(__uint_as_float(misc[1]));
    int* flagcnt = (int*)&misc[2];
    float part = 0.0f;

#pragma unroll 1
    for (int t = 0; t < 16; ++t) {
        const int token = tbase + t;
        float v1s[4], v2s[4], v3s[4];
        int   c1s[4], c2s[4];
#pragma unroll
        for (int s = 0; s < 4; ++s) {
            const Part P = parts[(size_t)token * SLICES + s];   // wave-uniform -> broadcast
            v1s[s] = P.v1;
            c1s[s] = s * SLICE_CODES + (int)(P.ii & 0xffffu);
            c2s[s] = s * SLICE_CODES + (int)(P.ii >> 16);
            v2s[s] = P.v1 + h_unpack(P.dd & 0xffffu);
            v3s[s] = P.v1 + h_unpack(P.dd >> 16);
        }
        float g1 = v1s[0];
#pragma unroll
        for (int s = 1; s < 4; ++s) g1 = fminf(g1, v1s[s]);

        const float2 nz = normz[token];
        const float Bnd = 2.0f * (sqrtf(nz.x) * maxCl + sqrtf(nz.y) * (maxCh + maxCl)) + SLACK;
        const float thresh = g1 + 2.0f * Bnd;
        const bool cert = (v3s[0] > thresh) && (v3s[1] > thresh) &&
                          (v3s[2] > thresh) && (v3s[3] > thresh);
        if (!cert) {
            if (lane == 0) { const int pos = atomicAdd(flagcnt, 1); list[pos] = token; }
        } else {
            const float4* zp = (const float4*)(z_e + (size_t)token * DIM);
            const float4 z0 = zp[lane], z1 = zp[lane + 64];
            float best = __builtin_inff(); int bc = 0x7fffffff;
            auto evalc = [&](int c) {
                const float4* cp = (const float4*)(cb + (size_t)c * DIM);
                const float4 c0v = cp[lane], c1v = cp[lane + 64];
                float p = z0.x*c0v.x + z0.y*c0v.y + z0.z*c0v.z + z0.w*c0v.w
                        + z1.x*c1v.x + z1.y*c1v.y + z1.z*c1v.z + z1.w*c1v.w;
#pragma unroll
                for (int off = 32; off > 0; off >>= 1) p += __shfl_down(p, off);
                p = __shfl(p, 0);
                const float sx = fmaf(-2.0f, p, nc[c]);
                if (sx < best || (sx == best && c < bc)) { best = sx; bc = c; }
            };
#pragma unroll 1
            for (int s = 0; s < 4; ++s) {
                if (v1s[s] <= thresh) evalc(c1s[s]);
                if (v2s[s] <= thresh) evalc(c2s[s]);
            }
            const float4* cp = (const float4*)(cb + (size_t)bc * DIM);
            const float4 q0 = cp[lane], q1 = cp[lane + 64];
            float4* op = (float4*)out + (size_t)token * (DIM / 4);
            op[lane] = q0; op[lane + 64] = q1;
            float dx = z0.x-q0.x, dy = z0.y-q0.y, dz = z0.z-q0.z, dw = z0.w-q0.w;
            part += dx*dx + dy*dy + dz*dz + dw*dw;
            dx = z1.x-q1.x; dy = z1.y-q1.y; dz = z1.z-q1.z; dw = z1.w-q1.w;
            part += dx*dx + dy*dy + dz*dz + dw*dw;
            if (lane == 0) out[OUT_IDX + token] = (float)bc;
        }
    }
#pragma unroll
    for (int off = 32; off > 0; off >>= 1) part += __shfl_down(part, off);
    if (lane == 0) wpart[wid] = part;
    __syncthreads();
    if (threadIdx.x == 0) atomicAdd(accum, wpart[0] + wpart[1] + wpart[2] + wpart[3]);
}

// ---------------------------------------------------------------------------
// Kernel 4: exact 3-pass f16-split GEMM (round-0-proven; ran+passed in r9).
// INDIRECT: token rows via flagged list. !INDIRECT+!PRESPLIT: full exact run
// (slow path when ws too small for ze planes).
template <bool INDIRECT, bool PRESPLIT>
__global__ __launch_bounds__(256, 2)
void vq_exact_kernel(const float* __restrict__ z_e,
                     const _Float16* __restrict__ ze_hi,
                     const _Float16* __restrict__ ze_lo,
                     const _Float16* __restrict__ cb_hi,
                     const _Float16* __restrict__ cb_lo,
                     const float* __restrict__ nc,
                     const int* __restrict__ list,
                     const int* __restrict__ pcnt,
                     float2* __restrict__ fpart) {
    int n;
    if constexpr (INDIRECT) { n = *pcnt; if (n > CAP_FLAG) n = CAP_FLAG; }
    else n = N_TOKENS;
    const int row0 = blockIdx.x * BMT;
    if (row0 >= n) return;   // uniform early exit, before any barrier

    __shared__ __align__(16) unsigned char smem[65536];
    _Float16* As_hi = (_Float16*)smem;
    _Float16* As_lo = (_Float16*)(smem + 16384);
    _Float16* Bs_hi = (_Float16*)(smem + 32768);
    _Float16* Bs_lo = (_Float16*)(smem + 49152);

    const int tid    = threadIdx.x;
    const int wid    = tid >> 6;
    const int lane   = tid & 63;
    const int wave_m = wid >> 1;
    const int wave_n = wid & 1;
    const int lane15 = lane & 15;
    const int quad   = lane >> 4;

    const int ns  = blockIdx.y;
    const int c00 = ns * SLICE_CODES;

    float minv[4][4];
    int   mini[4][4];
#pragma unroll
    for (int mi = 0; mi < 4; ++mi)
#pragma unroll
        for (int r = 0; r < 4; ++r) { minv[mi][r] = __builtin_inff(); mini[mi][r] = 0; }

    const int b_r8 = lane >> 3;
    const int b_g  = lane & 7;
    const int s_r0 = tid >> 4;
    const int s_cg = tid & 15;

#pragma unroll 1
    for (int nt = 0; nt < NTILES; ++nt) {
        const int c0 = c00 + nt * BNT;
        f32x4 acc[4][4];
#pragma unroll
        for (int mi = 0; mi < 4; ++mi)
#pragma unroll
            for (int ni = 0; ni < 4; ++ni) acc[mi][ni] = (f32x4){0.f, 0.f, 0.f, 0.f};

#pragma unroll 1
        for (int kc = 0; kc < CHUNKS; ++kc) {
            __syncthreads();
#pragma unroll
            for (int i = 0; i < 4; ++i) {
                const int L = wid * 4 + i;
                const int brow = L * 8 + b_r8;
                const size_t kb = (size_t)(c0 + brow) * DIM + kc * BK + ((b_g ^ (brow & 7)) << 3);
                async_copy16(Bs_hi + L * 512, cb_hi + kb);
                async_copy16(Bs_lo + L * 512, cb_lo + kb);
            }
            if constexpr (PRESPLIT) {
#pragma unroll
                for (int i = 0; i < 4; ++i) {
                    const int L = wid * 4 + i;
                    const int arow = L * 8 + b_r8;
                    int tok;
                    if constexpr (INDIRECT) {
                        const int pos = row0 + arow;
                        tok = (pos < n) ? list[pos] : 0;
                    } else tok = row0 + arow;
                    const size_t ka = (size_t)tok * DIM + kc * BK + ((b_g ^ (arow & 7)) << 3);
                    async_copy16(As_hi + L * 512, ze_hi + ka);
                    async_copy16(As_lo + L * 512, ze_lo + ka);
                }
            } else {
#pragma unroll
                for (int rr = 0; rr < 8; ++rr) {
                    const int row = rr * 16 + s_r0;
                    float4 v = *(const float4*)&z_e[(size_t)(row0 + row) * DIM + kc * BK + s_cg * 4];
                    f16x4 hi = {(_Float16)v.x, (_Float16)v.y, (_Float16)v.z, (_Float16)v.w};
                    f16x4 lo = {(_Float16)(v.x - (float)hi[0]), (_Float16)(v.y - (float)hi[1]),
                                (_Float16)(v.z - (float)hi[2]), (_Float16)(v.w - (float)hi[3])};
                    const int a = sw_idx(row, s_cg >> 1) + ((s_cg & 1) << 2);
                    *(f16x4*)&As_hi[a] = hi;
                    *(f16x4*)&As_lo[a] = lo;
                }
            }
            __syncthreads();

#pragma unroll
            for (int ks = 0; ks < 2; ++ks) {
                const int kg = ks * 4 + quad;
                f16x8 ah[4], al[4], bh[4], bl[4];
#pragma unroll
                for (int mi = 0; mi < 4; ++mi) {
                    const int a = sw_idx(wave_m * 64 + mi * 16 + lane15, kg);
                    ah[mi] = *(const f16x8*)&As_hi[a];
                    al[mi] = *(const f16x8*)&As_lo[a];
                }
#pragma unroll
                for (int ni = 0; ni < 4; ++ni) {
                    const int b = sw_idx(wave_n * 64 + ni * 16 + lane15, kg);
                    bh[ni] = *(const f16x8*)&Bs_hi[b];
                    bl[ni] = *(const f16x8*)&Bs_lo[b];
                }
#pragma unroll
                for (int mi = 0; mi < 4; ++mi)
#pragma unroll
                    for (int ni = 0; ni < 4; ++ni)
                        acc[mi][ni] = __builtin_amdgcn_mfma_f32_16x16x32_f16(ah[mi], bh[ni], acc[mi][ni], 0, 0, 0);
#pragma unroll
                for (int mi = 0; mi < 4; ++mi)
#pragma unroll
                    for (int ni = 0; ni < 4; ++ni)
                        acc[mi][ni] = __builtin_amdgcn_mfma_f32_16x16x32_f16(al[mi], bh[ni], acc[mi][ni], 0, 0, 0);
#pragma unroll
                for (int mi = 0; mi < 4; ++mi)
#pragma unroll
                    for (int ni = 0; ni < 4; ++ni)
                        acc[mi][ni] = __builtin_amdgcn_mfma_f32_16x16x32_f16(ah[mi], bl[ni], acc[mi][ni], 0, 0, 0);
            }
        }

#pragma unroll
        for (int ni = 0; ni < 4; ++ni) {
            const int c = c0 + wave_n * 64 + ni * 16 + lane15;
            const float nrm = nc[c];
#pragma unroll
            for (int mi = 0; mi < 4; ++mi)
#pragma unroll
                for (int r = 0; r < 4; ++r) {
                    const float v = fmaf(-2.0f, acc[mi][ni][r], nrm);
                    if (v < minv[mi][r]) { minv[mi][r] = v; mini[mi][r] = c; }
                }
        }
    }

    __syncthreads();
    float* redv = (float*)smem;
    int*   redi = (int*)(smem + 16384);
#pragma unroll
    for (int mi = 0; mi < 4; ++mi)
#pragma unroll
        for (int r = 0; r < 4; ++r) {
            const int rl = wave_m * 64 + mi * 16 + quad * 4 + r;
            const int o = wave_n * 2048 + rl * 16 + lane15;
            redv[o] = minv[mi][r];
            redi[o] = mini[mi][r];
        }
    __syncthreads();
    if (tid < BMT) {
        float bv = __builtin_inff();
        int   bi = 0x7fffffff;
        for (int j = 0; j < 32; ++j) {
            const int o = (j >= 16 ? 2048 : 0) + tid * 16 + (j & 15);
            const float v = redv[o];
            const int   i = redi[o];
            if (v < bv || (v == bv && i < bi)) { bv = v; bi = i; }
        }
        fpart[(size_t)(row0 + tid) * SLICES + ns] = make_float2(bv, __int_as_float(bi));
    }
}

// ---------------------------------------------------------------------------
// Kernel 5: exact merge for listed positions (or all tokens when !INDIRECT).
template <bool INDIRECT>
__global__ void vq_final_merge_kernel(const float* __restrict__ z_e,
                                      const float* __restrict__ cb,
                                      const float2* __restrict__ fpart,
                                      const int* __restrict__ list,
                                      const int* __restrict__ pcnt,
                                      float* __restrict__ out,
                                      float* __restrict__ accum) {
    __shared__ float wpart[4];
    int n;
    if constexpr (INDIRECT) { n = *pcnt; if (n > CAP_FLAG) n = CAP_FLAG; }
    else n = N_TOKENS;
    const int wid  = threadIdx.x >> 6;
    const int lane = threadIdx.x & 63;
    const int tbase = blockIdx.x * 64 + wid * 16;
    float part = 0.0f;
#pragma unroll 1
    for (int t = 0; t < 16; ++t) {
        const int pos = tbase + t;
        if (pos < n) {
            int token;
            if constexpr (INDIRECT) token = list[pos]; else token = pos;
            float bv = __builtin_inff();
            int   bi = 0x7fffffff;
#pragma unroll
            for (int s = 0; s < SLICES; ++s) {
                float2 p = fpart[(size_t)pos * SLICES + s];
                const float v = p.x; const int i = __float_as_int(p.y);
                if (v < bv || (v == bv && i < bi)) { bv = v; bi = i; }
            }
            const int code = bi & (N_CODES - 1);
            const float4* zp = (const float4*)(z_e + (size_t)token * DIM);
            const float4* cp = (const float4*)(cb + (size_t)code * DIM);
            float4* op = (float4*)out + (size_t)token * (DIM / 4);
#pragma unroll
            for (int i = 0; i < 2; ++i) {
                const int e = lane + i * 64;
                float4 z = zp[e];
                float4 q = cp[e];
                op[e] = q;
                float dx = z.x - q.x, dy = z.y - q.y, dz = z.z - q.z, dw = z.w - q.w;
                part += dx * dx + dy * dy + dz * dz + dw * dw;
            }
            if (lane == 0) out[OUT_IDX + token] = (float)code;
        }
    }
#pragma unroll
    for (int off = 32; off > 0; off >>= 1) part += __shfl_down(part, off);
    if (lane == 0) wpart[wid] = part;
    __syncthreads();
    if (threadIdx.x == 0) atomicAdd(accum, wpart[0] + wpart[1] + wpart[2] + wpart[3]);
}

// ---------------------------------------------------------------------------
// Kernel 6: finalize losses
__global__ void vq_finalize_kernel(const float* __restrict__ accum,
                                   float* __restrict__ out) {
    const float c = *accum * (1.0f / (float)(N_TOKENS * DIM));
    out[OUT_VQ]     = 0.25f * c;
    out[OUT_COMMIT] = c;
}

// ---------------------------------------------------------------------------
extern "C" void kernel_launch(void* const* d_in, const int* in_sizes, int n_in,
                              void* d_out, int out_size, void* d_ws, size_t ws_size,
                              hipStream_t stream) {
    const float* z_e = (const float*)d_in[0];
    const float* cb  = (const float*)d_in[1];
    float* out = (float*)d_out;

    _Float16*     cb_hi  = (_Float16*)((char*)d_ws + WS_CBHI);
    _Float16*     cb_lo  = (_Float16*)((char*)d_ws + WS_CBLO);
    float*        nc     = (float*)((char*)d_ws + WS_NC);
    float2*       normz  = (float2*)((char*)d_ws + WS_NORMZ);
    unsigned int* misc   = (unsigned int*)((char*)d_ws + WS_MISC);
    int*          list   = (int*)((char*)d_ws + WS_LIST);
    Part*         parts  = (Part*)((char*)d_ws + WS_PART);
    float2*       fpart  = (float2*)((char*)d_ws + WS_PART);   // reuse after merge consumed parts
    _Float16*     ze_hi  = (_Float16*)((char*)d_ws + WS_ZEHI);
    _Float16*     ze_lo  = (_Float16*)((char*)d_ws + WS_ZELO);
    int*          flagcnt = (int*)&misc[2];
    float*        accum   = (float*)&misc[3];

    const bool fast = (ws_size >= (size_t)WS_NEED_FAST);  // call-invariant -> graph-safe

    hipLaunchKernelGGL(vq_init_kernel, dim3(1), dim3(64), 0, stream, misc);
    hipLaunchKernelGGL(vq_prep_cb_kernel, dim3(N_CODES / 4), dim3(256), 0, stream,
                       cb, cb_hi, cb_lo, nc, misc);
    if (fast) {
        hipLaunchKernelGGL(vq_prep_ze_kernel, dim3(N_TOKENS / 4), dim3(256), 0, stream,
                           z_e, ze_hi, ze_lo, normz);
        hipLaunchKernelGGL(vq_main_hi_kernel, dim3(N_TOKENS / BMT, SLICES), dim3(256), 0, stream,
                           ze_hi, cb_hi, nc, parts);
        hipLaunchKernelGGL(vq_merge_cert_kernel, dim3(N_TOKENS / 64), dim3(256), 0, stream,
                           z_e, cb, nc, parts, normz, misc, list, out, accum);
        hipLaunchKernelGGL((vq_exact_kernel<true, true>), dim3(CAP_FLAG / BMT, SLICES), dim3(256), 0, stream,
                           z_e, ze_hi, ze_lo, cb_hi, cb_lo, nc, list, flagcnt, fpart);
        hipLaunchKernelGGL((vq_final_merge_kernel<true>), dim3(CAP_FLAG / 64), dim3(256), 0, stream,
                           z_e, cb, fpart, list, flagcnt, out, accum);
    } else {
        hipLaunchKernelGGL((vq_exact_kernel<false, false>), dim3(N_TOKENS / BMT, SLICES), dim3(256), 0, stream,
                           z_e, ze_hi, ze_lo, cb_hi, cb_lo, nc, (const int*)nullptr, (const int*)nullptr, fpart);
        hipLaunchKernelGGL((vq_final_merge_kernel<false>), dim3(N_TOKENS / 64), dim3(256), 0, stream,
                           z_e, cb, fpart, (const int*)nullptr, (const int*)nullptr, out, accum);
    }
    hipLaunchKernelGGL(vq_finalize_kernel, dim3(1), dim3(1), 0, stream, accum, out);
}

// Round 12
// 867.768 us; speedup vs baseline: 1.3250x; 1.3250x over previous
//
#include <hip/hip_runtime.h>

// Problem constants (fixed by the reference)
#define N_TOKENS 32768
#define N_CODES  8192
#define DIM      512

// GEMM tiling (round-0-proven 128x128, BK=64, 2 blocks/CU)
#define BMT 128
#define BNT 128
#define SLICES 4
#define SLICE_CODES (N_CODES / SLICES)   // 2048
#define NTILES (SLICE_CODES / BNT)       // 16
#define BK 64
#define CHUNKS (DIM / BK)                // 8

#define CAP_FLAG 32768                   // flagged capacity = ALL tokens
#define SLACK 0.25f                      // covers MFMA accum / fp32 rounding (~1e-3, big margin)

// Output layout (FP32 elements, reference return order)
#define OUT_VQ     16777216
#define OUT_COMMIT 16777217
#define OUT_IDX    16777218

// Workspace byte offsets (identical envelope to rounds 0-10: 85,983,232)
#define WS_CBHI   0                      //  8 MB codebook f16 hi
#define WS_CBLO   8388608                //  8 MB codebook f16 lo
#define WS_NC     16777216               // 32 KB exact fp32 code norms
#define WS_NORMZ  16809984               // 256 KB per-token (|zh|^2,|zl|^2); REUSED as u64 fexact keys
#define WS_MISC   17072128               // 16 B: [0] max|cl|^2 [1] max|ch|^2 [2] flagcnt [3] accum
#define WS_LIST   17072144               // 128 KB flagged-token list (32768 ints)
#define WS_PART   17301504               // 1.5 MB Part[32768][4] (12B); reused as float2 fpart (slow path)
#define WS_ZEHI   18874368               // 32 MB z_e f16 hi
#define WS_ZELO   52428800               // 32 MB z_e f16 lo (ends 85983232)
#define WS_NEED_FAST 85983232

typedef _Float16 f16x8 __attribute__((ext_vector_type(8)));
typedef _Float16 f16x4 __attribute__((ext_vector_type(4)));
typedef float    f32x4 __attribute__((ext_vector_type(4)));

// Per-(token, slice) summary: v1 + idx1/idx2 (slice-local) + packed deltas:
// dd lo16 = floor16(v2-v1), dd hi16 = floor16(w-v1) where w = exclusion bound
// (min of union-3rd-value and min-slot-v2). FLOOR-rounding keeps cert conservative.
struct Part { float v1; unsigned int ii; unsigned int dd; };   // 12 B

// floor-rounding float -> f16 bits (x >= 0)
__device__ __forceinline__ unsigned short h_floor(float x) {
    union { _Float16 h; unsigned short b; } u;
    u.h = (_Float16)x;                       // nearest
    if ((float)u.h > x && u.b) --u.b;        // positive halfs: bits-- = next smaller
    return u.b;
}
__device__ __forceinline__ float h_unpack(unsigned int b) {
    union { unsigned short b; _Float16 h; } u;
    u.b = (unsigned short)b;
    return (float)u.h;
}

// order-preserving float -> uint (monotone for all finite floats)
__device__ __forceinline__ unsigned int ford(float v) {
    unsigned int b = __float_as_uint(v);
    return (b & 0x80000000u) ? ~b : (b | 0x80000000u);
}

// XOR-swizzled LDS half-index for (row, kgrp of 8 halves); row stride 128B.
__device__ __forceinline__ int sw_idx(int row, int kgrp) {
    return row * 64 + ((kgrp ^ (row & 7)) << 3);
}

// async 16B global->LDS (lds dest = wave-uniform base + lane*16; global src per-lane)
__device__ __forceinline__ void async_copy16(void* lds, const void* g) {
    __builtin_amdgcn_global_load_lds(
        (const __attribute__((address_space(1))) unsigned int*)g,
        (__attribute__((address_space(3))) unsigned int*)lds,
        16, 0, 0);
}

// ---------------------------------------------------------------------------
__global__ void vq_init_kernel(unsigned int* misc) {
    if (threadIdx.x < 4) misc[threadIdx.x] = 0u;
}

// ---------------------------------------------------------------------------
// Kernel 1a: codebook -> f16 hi/lo planes + exact norms + global max split-norms.
__global__ void vq_prep_cb_kernel(const float* __restrict__ cb,
                                  _Float16* __restrict__ cb_hi,
                                  _Float16* __restrict__ cb_lo,
                                  float* __restrict__ nc,
                                  unsigned int* __restrict__ misc) {
    const int wid  = threadIdx.x >> 6;
    const int lane = threadIdx.x & 63;
    const int row  = blockIdx.x * 4 + wid;
    const float4* src = (const float4*)(cb + (size_t)row * DIM);
    float4 v0 = src[lane * 2];
    float4 v1 = src[lane * 2 + 1];
    float s = v0.x*v0.x + v0.y*v0.y + v0.z*v0.z + v0.w*v0.w
            + v1.x*v1.x + v1.y*v1.y + v1.z*v1.z + v1.w*v1.w;
    f16x8 hi = {(_Float16)v0.x, (_Float16)v0.y, (_Float16)v0.z, (_Float16)v0.w,
                (_Float16)v1.x, (_Float16)v1.y, (_Float16)v1.z, (_Float16)v1.w};
    float h0=(float)hi[0], h1=(float)hi[1], h2=(float)hi[2], h3=(float)hi[3];
    float h4=(float)hi[4], h5=(float)hi[5], h6=(float)hi[6], h7=(float)hi[7];
    float l0=v0.x-h0, l1=v0.y-h1, l2=v0.z-h2, l3=v0.w-h3;
    float l4=v1.x-h4, l5=v1.y-h5, l6=v1.z-h6, l7=v1.w-h7;
    f16x8 lo = {(_Float16)l0,(_Float16)l1,(_Float16)l2,(_Float16)l3,
                (_Float16)l4,(_Float16)l5,(_Float16)l6,(_Float16)l7};
    *(f16x8*)&cb_hi[(size_t)row * DIM + lane * 8] = hi;
    *(f16x8*)&cb_lo[(size_t)row * DIM + lane * 8] = lo;
    float sh = h0*h0+h1*h1+h2*h2+h3*h3+h4*h4+h5*h5+h6*h6+h7*h7;
    float sl = l0*l0+l1*l1+l2*l2+l3*l3+l4*l4+l5*l5+l6*l6+l7*l7;
#pragma unroll
    for (int off = 32; off > 0; off >>= 1) {
        s  += __shfl_down(s, off);
        sh += __shfl_down(sh, off);
        sl += __shfl_down(sl, off);
    }
    if (lane == 0) {
        nc[row] = s;
        atomicMax(&misc[0], __float_as_uint(sl));  // max ||c_lo||^2
        atomicMax(&misc[1], __float_as_uint(sh));  // max ||c_hi||^2
    }
}

// Kernel 1b: z_e -> f16 hi/lo planes + per-token split norms (fast path only).
__global__ void vq_prep_ze_kernel(const float* __restrict__ z_e,
                                  _Float16* __restrict__ ze_hi,
                                  _Float16* __restrict__ ze_lo,
                                  float2* __restrict__ normz) {
    const int wid  = threadIdx.x >> 6;
    const int lane = threadIdx.x & 63;
    const int row  = blockIdx.x * 4 + wid;
    const float4* src = (const float4*)(z_e + (size_t)row * DIM);
    float4 v0 = src[lane * 2];
    float4 v1 = src[lane * 2 + 1];
    f16x8 hi = {(_Float16)v0.x, (_Float16)v0.y, (_Float16)v0.z, (_Float16)v0.w,
                (_Float16)v1.x, (_Float16)v1.y, (_Float16)v1.z, (_Float16)v1.w};
    float h0=(float)hi[0], h1=(float)hi[1], h2=(float)hi[2], h3=(float)hi[3];
    float h4=(float)hi[4], h5=(float)hi[5], h6=(float)hi[6], h7=(float)hi[7];
    float l0=v0.x-h0, l1=v0.y-h1, l2=v0.z-h2, l3=v0.w-h3;
    float l4=v1.x-h4, l5=v1.y-h5, l6=v1.z-h6, l7=v1.w-h7;
    f16x8 lo = {(_Float16)l0,(_Float16)l1,(_Float16)l2,(_Float16)l3,
                (_Float16)l4,(_Float16)l5,(_Float16)l6,(_Float16)l7};
    *(f16x8*)&ze_hi[(size_t)row * DIM + lane * 8] = hi;
    *(f16x8*)&ze_lo[(size_t)row * DIM + lane * 8] = lo;
    float sh = h0*h0+h1*h1+h2*h2+h3*h3+h4*h4+h5*h5+h6*h6+h7*h7;
    float sl = l0*l0+l1*l1+l2*l2+l3*l3+l4*l4+l5*l5+l6*l6+l7*l7;
#pragma unroll
    for (int off = 32; off > 0; off >>= 1) {
        sh += __shfl_down(sh, off);
        sl += __shfl_down(sl, off);
    }
    if (lane == 0) normz[row] = make_float2(sh, sl);
}

// ---------------------------------------------------------------------------
// Kernel 2: 1-pass hi*hi GEMM + per-slot TOP-2(+idx); block reduction builds
// slice (v1,i1,v2,i2) and exclusion bound w = min(union_v3, min_slot_v2).
// Hot loop = r9's proven cheap top-2 (+1 idx move); heavy logic only in the
// once-per-block reduction (r10's in-loop top-3 cost +100us — reverted).
__global__ __launch_bounds__(256, 2)
void vq_main_hi_kernel(const _Float16* __restrict__ ze_hi,
                       const _Float16* __restrict__ cb_hi,
                       const float* __restrict__ nc,
                       Part* __restrict__ parts) {
    // GEMM: 32KB (As+Bs). Reduction: 4 arrays x 8KB = 32KB (reused).
    __shared__ __align__(16) unsigned char smem[49152];
    _Float16* As = (_Float16*)smem;           // [128][64] halves
    _Float16* Bs = (_Float16*)smem + 8192;

    const int tid    = threadIdx.x;
    const int wid    = tid >> 6;
    const int lane   = tid & 63;
    const int wave_m = wid >> 1;
    const int wave_n = wid & 1;
    const int lane15 = lane & 15;
    const int quad   = lane >> 4;

    const int ns   = blockIdx.y;
    const int row0 = blockIdx.x * BMT;
    const int c00  = ns * SLICE_CODES;

    float tv1[4][4], tv2[4][4];
    int   ti1[4][4], ti2[4][4];
#pragma unroll
    for (int mi = 0; mi < 4; ++mi)
#pragma unroll
        for (int r = 0; r < 4; ++r) {
            tv1[mi][r] = __builtin_inff(); tv2[mi][r] = __builtin_inff();
            ti1[mi][r] = c00; ti2[mi][r] = c00;
        }

    const int b_r8 = lane >> 3;
    const int b_g  = lane & 7;

#pragma unroll 1
    for (int nt = 0; nt < NTILES; ++nt) {
        const int c0 = c00 + nt * BNT;
        f32x4 acc[4][4];
#pragma unroll
        for (int mi = 0; mi < 4; ++mi)
#pragma unroll
            for (int ni = 0; ni < 4; ++ni) acc[mi][ni] = (f32x4){0.f, 0.f, 0.f, 0.f};

#pragma unroll 1
        for (int kc = 0; kc < CHUNKS; ++kc) {
            __syncthreads();
#pragma unroll
            for (int i = 0; i < 4; ++i) {
                const int L = wid * 4 + i;
                const int row = L * 8 + b_r8;
                const int g = (b_g ^ (row & 7)) << 3;
                async_copy16(Bs + L * 512, cb_hi + (size_t)(c0 + row) * DIM + kc * BK + g);
                async_copy16(As + L * 512, ze_hi + (size_t)(row0 + row) * DIM + kc * BK + g);
            }
            __syncthreads();

#pragma unroll
            for (int ks = 0; ks < 2; ++ks) {
                const int kg = ks * 4 + quad;
                f16x8 ah[4], bh[4];
#pragma unroll
                for (int mi = 0; mi < 4; ++mi)
                    ah[mi] = *(const f16x8*)&As[sw_idx(wave_m * 64 + mi * 16 + lane15, kg)];
#pragma unroll
                for (int ni = 0; ni < 4; ++ni)
                    bh[ni] = *(const f16x8*)&Bs[sw_idx(wave_n * 64 + ni * 16 + lane15, kg)];
#pragma unroll
                for (int mi = 0; mi < 4; ++mi)
#pragma unroll
                    for (int ni = 0; ni < 4; ++ni)
                        acc[mi][ni] = __builtin_amdgcn_mfma_f32_16x16x32_f16(
                            ah[mi], bh[ni], acc[mi][ni], 0, 0, 0);
            }
        }

        // cheap slot top-2 (+idx) update
#pragma unroll
        for (int ni = 0; ni < 4; ++ni) {
            const int c = c0 + wave_n * 64 + ni * 16 + lane15;
            const float nrm = nc[c];
#pragma unroll
            for (int mi = 0; mi < 4; ++mi)
#pragma unroll
                for (int r = 0; r < 4; ++r) {
                    const float v = fmaf(-2.0f, acc[mi][ni][r], nrm);
                    if (v < tv1[mi][r]) {
                        tv2[mi][r] = tv1[mi][r]; ti2[mi][r] = ti1[mi][r];
                        tv1[mi][r] = v;          ti1[mi][r] = c;
                    } else if (v < tv2[mi][r]) {
                        tv2[mi][r] = v;          ti2[mi][r] = c;
                    }
                }
        }
    }

    // block reduction, two row-halves: arrays [2 wave_n][64 rows][16 lanes]
    float* rv1 = (float*)smem;
    float* rv2 = rv1 + 2048;
    int*   ri1 = (int*)(rv2 + 2048);
    int*   ri2 = ri1 + 2048;

#pragma unroll 1
    for (int half = 0; half < 2; ++half) {
        __syncthreads();   // also protects GEMM smem reuse on first iteration
        if (wave_m == half) {
#pragma unroll
            for (int mi = 0; mi < 4; ++mi)
#pragma unroll
                for (int r = 0; r < 4; ++r) {
                    const int rl = mi * 16 + quad * 4 + r;          // row within half
                    const int o  = wave_n * 1024 + rl * 16 + lane15;
                    rv1[o] = tv1[mi][r]; rv2[o] = tv2[mi][r];
                    ri1[o] = ti1[mi][r]; ri2[o] = ti2[mi][r];
                }
        }
        __syncthreads();
        if (tid < 64) {
            float v1 = __builtin_inff(), v2 = __builtin_inff(), v3 = __builtin_inff();
            float w2 = __builtin_inff();
            int   i1 = c00, i2 = c00;
            auto ins = [&](float v, int i) {
                if (v < v1) { v3 = v2; v2 = v1; i2 = i1; v1 = v; i1 = i; }
                else if (v < v2) { v3 = v2; v2 = v; i2 = i; }
                else if (v < v3) { v3 = v; }
            };
            for (int j = 0; j < 32; ++j) {
                const int o = (j >= 16 ? 1024 : 0) + tid * 16 + (j & 15);
                const float a = rv1[o]; const int ia = ri1[o];
                const float b = rv2[o]; const int ib = ri2[o];
                ins(a, ia);
                ins(b, ib);
                w2 = fminf(w2, b);      // min over slot-v2s (exclusion case A)
            }
            const float w = fminf(v3, w2);   // exclusion bound for non-candidates
            Part P;
            P.v1 = v1;
            P.ii = (unsigned int)(i1 - c00) | ((unsigned int)(i2 - c00) << 16);
            P.dd = (unsigned int)h_floor(v2 - v1) | ((unsigned int)h_floor(w - v1) << 16);
            parts[(size_t)(row0 + half * 64 + tid) * SLICES + ns] = P;
        }
    }
}

// ---------------------------------------------------------------------------
// Kernel 3: certify + refine merge.
// Any non-candidate code has s_hi >= w (per-slice). cert: every slice's
// w' > thresh = g1 + 2B  =>  true argmin is among {i1,i2} x 4 slices;
// refine those with value <= thresh using exact fp32 dots. Else flag token
// (and init its u64 exact-key slot).
__global__ void vq_merge_cert_kernel(const float* __restrict__ z_e,
                                     const float* __restrict__ cb,
                                     const float* __restrict__ nc,
                                     const Part* __restrict__ parts,
                                     const float2* __restrict__ normz,
                                     unsigned long long* __restrict__ fexact,
                                     unsigned int* __restrict__ misc,
                                     int* __restrict__ list,
                                     float* __restrict__ out,
                                     float* __restrict__ accum) {
    __shared__ float wpart[4];
    const int wid  = threadIdx.x >> 6;
    const int lane = threadIdx.x & 63;
    const int tbase = blockIdx.x * 64 + wid * 16;
    const float maxCl = sqrtf(__uint_as_float(misc[0]));
    const float maxCh = sqrtf(__uint_as_float(misc[1]));
    int* flagcnt = (int*)&misc[2];
    float part = 0.0f;

#pragma unroll 1
    for (int t = 0; t < 16; ++t) {
        const int token = tbase + t;
        float v1s[4], v2s[4], ws[4];
        int   c1s[4], c2s[4];
#pragma unroll
        for (int s = 0; s < 4; ++s) {
            const Part P = parts[(size_t)token * SLICES + s];   // wave-uniform
            v1s[s] = P.v1;
            c1s[s] = s * SLICE_CODES + (int)(P.ii & 0xffffu);
            c2s[s] = s * SLICE_CODES + (int)(P.ii >> 16);
            v2s[s] = P.v1 + h_unpack(P.dd & 0xffffu);
            ws[s]  = P.v1 + h_unpack(P.dd >> 16);
        }
        float g1 = v1s[0];
#pragma unroll
        for (int s = 1; s < 4; ++s) g1 = fminf(g1, v1s[s]);

        const float2 nz = normz[token];   // read BEFORE any fexact overwrite (same slot)
        const float Bnd = 2.0f * (sqrtf(nz.x) * maxCl + sqrtf(nz.y) * (maxCh + maxCl)) + SLACK;
        const float thresh = g1 + 2.0f * Bnd;
        const bool cert = (ws[0] > thresh) && (ws[1] > thresh) &&
                          (ws[2] > thresh) && (ws[3] > thresh);
        if (!cert) {
            if (lane == 0) {
                const int pos = atomicAdd(flagcnt, 1);
                list[pos] = token;
                fexact[token] = ~0ull;    // init key slot (aliases this token's normz)
            }
        } else {
            const float4* zp = (const float4*)(z_e + (size_t)token * DIM);
            const float4 z0 = zp[lane], z1 = zp[lane + 64];
            float best = __builtin_inff(); int bc = 0x7fffffff;
            auto evalc = [&](int c) {
                const float4* cp = (const float4*)(cb + (size_t)c * DIM);
                const float4 c0v = cp[lane], c1v = cp[lane + 64];
                float p = z0.x*c0v.x + z0.y*c0v.y + z0.z*c0v.z + z0.w*c0v.w
                        + z1.x*c1v.x + z1.y*c1v.y + z1.z*c1v.z + z1.w*c1v.w;
#pragma unroll
                for (int off = 32; off > 0; off >>= 1) p += __shfl_down(p, off);
                p = __shfl(p, 0);
                const float sx = fmaf(-2.0f, p, nc[c]);
                if (sx < best || (sx == best && c < bc)) { best = sx; bc = c; }
            };
#pragma unroll 1
            for (int s = 0; s < 4; ++s) {
                if (v1s[s] <= thresh) evalc(c1s[s]);
                if (v2s[s] <= thresh) evalc(c2s[s]);
            }
            const float4* cp = (const float4*)(cb + (size_t)bc * DIM);
            const float4 q0 = cp[lane], q1 = cp[lane + 64];
            float4* op = (float4*)out + (size_t)token * (DIM / 4);
            op[lane] = q0; op[lane + 64] = q1;
            float dx = z0.x-q0.x, dy = z0.y-q0.y, dz = z0.z-q0.z, dw = z0.w-q0.w;
            part += dx*dx + dy*dy + dz*dz + dw*dw;
            dx = z1.x-q1.x; dy = z1.y-q1.y; dz = z1.z-q1.z; dw = z1.w-q1.w;
            part += dx*dx + dy*dy + dz*dz + dw*dw;
            if (lane == 0) out[OUT_IDX + token] = (float)bc;
        }
    }
#pragma unroll
    for (int off = 32; off > 0; off >>= 1) part += __shfl_down(part, off);
    if (lane == 0) wpart[wid] = part;
    __syncthreads();
    if (threadIdx.x == 0) atomicAdd(accum, wpart[0] + wpart[1] + wpart[2] + wpart[3]);
}

// ---------------------------------------------------------------------------
// Kernel 4a (fast fallback): exact 3-pass f16-split GEMM over flagged tokens,
// FINE-GRAINED: grid (token-tiles x 32 code-groups of 256). Per-block serial
// depth = 16 chunk-steps (~60us wall) vs r10's 128 (~360us) — the exact
// fallback's wall time is its serial depth, not its token count.
// Block winners combine via per-token u64 atomicMin (ord(v)<<13 | code).
__global__ __launch_bounds__(256, 2)
void vq_exact_fine_kernel(const _Float16* __restrict__ ze_hi,
                          const _Float16* __restrict__ ze_lo,
                          const _Float16* __restrict__ cb_hi,
                          const _Float16* __restrict__ cb_lo,
                          const float* __restrict__ nc,
                          const int* __restrict__ list,
                          const int* __restrict__ pcnt,
                          unsigned long long* __restrict__ fexact) {
    int n = *pcnt; if (n > CAP_FLAG) n = CAP_FLAG;
    const int row0 = blockIdx.x * BMT;
    if (row0 >= n) return;   // uniform early exit, before any barrier

    __shared__ __align__(16) unsigned char smem[65536];
    _Float16* As_hi = (_Float16*)smem;
    _Float16* As_lo = (_Float16*)(smem + 16384);
    _Float16* Bs_hi = (_Float16*)(smem + 32768);
    _Float16* Bs_lo = (_Float16*)(smem + 49152);

    const int tid    = threadIdx.x;
    const int wid    = tid >> 6;
    const int lane   = tid & 63;
    const int wave_m = wid >> 1;
    const int wave_n = wid & 1;
    const int lane15 = lane & 15;
    const int quad   = lane >> 4;

    const int c00 = blockIdx.y * 256;    // 256-code group

    float minv[4][4];
    int   mini[4][4];
#pragma unroll
    for (int mi = 0; mi < 4; ++mi)
#pragma unroll
        for (int r = 0; r < 4; ++r) { minv[mi][r] = __builtin_inff(); mini[mi][r] = 0; }

    const int b_r8 = lane >> 3;
    const int b_g  = lane & 7;

#pragma unroll 1
    for (int nt = 0; nt < 2; ++nt) {
        const int c0 = c00 + nt * BNT;
        f32x4 acc[4][4];
#pragma unroll
        for (int mi = 0; mi < 4; ++mi)
#pragma unroll
            for (int ni = 0; ni < 4; ++ni) acc[mi][ni] = (f32x4){0.f, 0.f, 0.f, 0.f};

#pragma unroll 1
        for (int kc = 0; kc < CHUNKS; ++kc) {
            __syncthreads();
#pragma unroll
            for (int i = 0; i < 4; ++i) {
                const int L = wid * 4 + i;
                const int brow = L * 8 + b_r8;
                const size_t kb = (size_t)(c0 + brow) * DIM + kc * BK + ((b_g ^ (brow & 7)) << 3);
                async_copy16(Bs_hi + L * 512, cb_hi + kb);
                async_copy16(Bs_lo + L * 512, cb_lo + kb);
                const int arow = brow;
                const int pos = row0 + arow;
                const int tok = (pos < n) ? list[pos] : 0;
                const size_t ka = (size_t)tok * DIM + kc * BK + ((b_g ^ (arow & 7)) << 3);
                async_copy16(As_hi + L * 512, ze_hi + ka);
                async_copy16(As_lo + L * 512, ze_lo + ka);
            }
            __syncthreads();

#pragma unroll
            for (int ks = 0; ks < 2; ++ks) {
                const int kg = ks * 4 + quad;
                f16x8 ah[4], al[4], bh[4], bl[4];
#pragma unroll
                for (int mi = 0; mi < 4; ++mi) {
                    const int a = sw_idx(wave_m * 64 + mi * 16 + lane15, kg);
                    ah[mi] = *(const f16x8*)&As_hi[a];
                    al[mi] = *(const f16x8*)&As_lo[a];
                }
#pragma unroll
                for (int ni = 0; ni < 4; ++ni) {
                    const int b = sw_idx(wave_n * 64 + ni * 16 + lane15, kg);
                    bh[ni] = *(const f16x8*)&Bs_hi[b];
                    bl[ni] = *(const f16x8*)&Bs_lo[b];
                }
#pragma unroll
                for (int mi = 0; mi < 4; ++mi)
#pragma unroll
                    for (int ni = 0; ni < 4; ++ni)
                        acc[mi][ni] = __builtin_amdgcn_mfma_f32_16x16x32_f16(ah[mi], bh[ni], acc[mi][ni], 0, 0, 0);
#pragma unroll
                for (int mi = 0; mi < 4; ++mi)
#pragma unroll
                    for (int ni = 0; ni < 4; ++ni)
                        acc[mi][ni] = __builtin_amdgcn_mfma_f32_16x16x32_f16(al[mi], bh[ni], acc[mi][ni], 0, 0, 0);
#pragma unroll
                for (int mi = 0; mi < 4; ++mi)
#pragma unroll
                    for (int ni = 0; ni < 4; ++ni)
                        acc[mi][ni] = __builtin_amdgcn_mfma_f32_16x16x32_f16(ah[mi], bl[ni], acc[mi][ni], 0, 0, 0);
            }
        }

#pragma unroll
        for (int ni = 0; ni < 4; ++ni) {
            const int c = c0 + wave_n * 64 + ni * 16 + lane15;
            const float nrm = nc[c];
#pragma unroll
            for (int mi = 0; mi < 4; ++mi)
#pragma unroll
                for (int r = 0; r < 4; ++r) {
                    const float v = fmaf(-2.0f, acc[mi][ni][r], nrm);
                    if (v < minv[mi][r]) { minv[mi][r] = v; mini[mi][r] = c; }
                }
        }
    }

    __syncthreads();
    float* redv = (float*)smem;
    int*   redi = (int*)(smem + 16384);
#pragma unroll
    for (int mi = 0; mi < 4; ++mi)
#pragma unroll
        for (int r = 0; r < 4; ++r) {
            const int rl = wave_m * 64 + mi * 16 + quad * 4 + r;
            const int o = wave_n * 2048 + rl * 16 + lane15;
            redv[o] = minv[mi][r];
            redi[o] = mini[mi][r];
        }
    __syncthreads();
    if (tid < BMT && row0 + tid < n) {
        float bv = __builtin_inff();
        int   bi = 0x7fffffff;
        for (int j = 0; j < 32; ++j) {
            const int o = (j >= 16 ? 2048 : 0) + tid * 16 + (j & 15);
            const float v = redv[o];
            const int   i = redi[o];
            if (v < bv || (v == bv && i < bi)) { bv = v; bi = i; }
        }
        const int token = list[row0 + tid];
        const unsigned long long key = ((unsigned long long)ford(bv) << 13) | (unsigned)bi;
        atomicMin(&fexact[token], key);
    }
}

// Kernel 5a (fast): resolve flagged tokens from u64 keys; gather + loss.
__global__ void vq_final_flag_kernel(const float* __restrict__ z_e,
                                     const float* __restrict__ cb,
                                     const unsigned long long* __restrict__ fexact,
                                     const int* __restrict__ list,
                                     const int* __restrict__ pcnt,
                                     float* __restrict__ out,
                                     float* __restrict__ accum) {
    __shared__ float wpart[4];
    int n = *pcnt; if (n > CAP_FLAG) n = CAP_FLAG;
    const int wid  = threadIdx.x >> 6;
    const int lane = threadIdx.x & 63;
    const int tbase = blockIdx.x * 64 + wid * 16;
    float part = 0.0f;
#pragma unroll 1
    for (int t = 0; t < 16; ++t) {
        const int pos = tbase + t;
        if (pos < n) {
            const int token = list[pos];
            const int code = (int)(fexact[token] & 0x1FFFull);
            const float4* zp = (const float4*)(z_e + (size_t)token * DIM);
            const float4* cp = (const float4*)(cb + (size_t)code * DIM);
            float4* op = (float4*)out + (size_t)token * (DIM / 4);
#pragma unroll
            for (int i = 0; i < 2; ++i) {
                const int e = lane + i * 64;
                float4 z = zp[e];
                float4 q = cp[e];
                op[e] = q;
                float dx = z.x - q.x, dy = z.y - q.y, dz = z.z - q.z, dw = z.w - q.w;
                part += dx * dx + dy * dy + dz * dz + dw * dw;
            }
            if (lane == 0) out[OUT_IDX + token] = (float)code;
        }
    }
#pragma unroll
    for (int off = 32; off > 0; off >>= 1) part += __shfl_down(part, off);
    if (lane == 0) wpart[wid] = part;
    __syncthreads();
    if (threadIdx.x == 0) atomicAdd(accum, wpart[0] + wpart[1] + wpart[2] + wpart[3]);
}

// ---------------------------------------------------------------------------
// Kernel 4b (slow path): full exact 3-pass GEMM, all tokens, in-kernel A split.
__global__ __launch_bounds__(256, 2)
void vq_exact_full_kernel(const float* __restrict__ z_e,
                          const _Float16* __restrict__ cb_hi,
                          const _Float16* __restrict__ cb_lo,
                          const float* __restrict__ nc,
                          float2* __restrict__ fpart) {
    __shared__ __align__(16) unsigned char smem[65536];
    _Float16* As_hi = (_Float16*)smem;
    _Float16* As_lo = (_Float16*)(smem + 16384);
    _Float16* Bs_hi = (_Float16*)(smem + 32768);
    _Float16* Bs_lo = (_Float16*)(smem + 49152);

    const int tid    = threadIdx.x;
    const int wid    = tid >> 6;
    const int lane   = tid & 63;
    const int wave_m = wid >> 1;
    const int wave_n = wid & 1;
    const int lane15 = lane & 15;
    const int quad   = lane >> 4;

    const int row0 = blockIdx.x * BMT;
    const int ns  = blockIdx.y;
    const int c00 = ns * SLICE_CODES;

    float minv[4][4];
    int   mini[4][4];
#pragma unroll
    for (int mi = 0; mi < 4; ++mi)
#pragma unroll
        for (int r = 0; r < 4; ++r) { minv[mi][r] = __builtin_inff(); mini[mi][r] = 0; }

    const int b_r8 = lane >> 3;
    const int b_g  = lane & 7;
    const int s_r0 = tid >> 4;
    const int s_cg = tid & 15;

#pragma unroll 1
    for (int nt = 0; nt < NTILES; ++nt) {
        const int c0 = c00 + nt * BNT;
        f32x4 acc[4][4];
#pragma unroll
        for (int mi = 0; mi < 4; ++mi)
#pragma unroll
            for (int ni = 0; ni < 4; ++ni) acc[mi][ni] = (f32x4){0.f, 0.f, 0.f, 0.f};

#pragma unroll 1
        for (int kc = 0; kc < CHUNKS; ++kc) {
            __syncthreads();
#pragma unroll
            for (int i = 0; i < 4; ++i) {
                const int L = wid * 4 + i;
                const int brow = L * 8 + b_r8;
                const size_t kb = (size_t)(c0 + brow) * DIM + kc * BK + ((b_g ^ (brow & 7)) << 3);
                async_copy16(Bs_hi + L * 512, cb_hi + kb);
                async_copy16(Bs_lo + L * 512, cb_lo + kb);
            }
#pragma unroll
            for (int rr = 0; rr < 8; ++rr) {
                const int row = rr * 16 + s_r0;
                float4 v = *(const float4*)&z_e[(size_t)(row0 + row) * DIM + kc * BK + s_cg * 4];
                f16x4 hi = {(_Float16)v.x, (_Float16)v.y, (_Float16)v.z, (_Float16)v.w};
                f16x4 lo = {(_Float16)(v.x - (float)hi[0]), (_Float16)(v.y - (float)hi[1]),
                            (_Float16)(v.z - (float)hi[2]), (_Float16)(v.w - (float)hi[3])};
                const int a = sw_idx(row, s_cg >> 1) + ((s_cg & 1) << 2);
                *(f16x4*)&As_hi[a] = hi;
                *(f16x4*)&As_lo[a] = lo;
            }
            __syncthreads();

#pragma unroll
            for (int ks = 0; ks < 2; ++ks) {
                const int kg = ks * 4 + quad;
                f16x8 ah[4], al[4], bh[4], bl[4];
#pragma unroll
                for (int mi = 0; mi < 4; ++mi) {
                    const int a = sw_idx(wave_m * 64 + mi * 16 + lane15, kg);
                    ah[mi] = *(const f16x8*)&As_hi[a];
                    al[mi] = *(const f16x8*)&As_lo[a];
                }
#pragma unroll
                for (int ni = 0; ni < 4; ++ni) {
                    const int b = sw_idx(wave_n * 64 + ni * 16 + lane15, kg);
                    bh[ni] = *(const f16x8*)&Bs_hi[b];
                    bl[ni] = *(const f16x8*)&Bs_lo[b];
                }
#pragma unroll
                for (int mi = 0; mi < 4; ++mi)
#pragma unroll
                    for (int ni = 0; ni < 4; ++ni)
                        acc[mi][ni] = __builtin_amdgcn_mfma_f32_16x16x32_f16(ah[mi], bh[ni], acc[mi][ni], 0, 0, 0);
#pragma unroll
                for (int mi = 0; mi < 4; ++mi)
#pragma unroll
                    for (int ni = 0; ni < 4; ++ni)
                        acc[mi][ni] = __builtin_amdgcn_mfma_f32_16x16x32_f16(al[mi], bh[ni], acc[mi][ni], 0, 0, 0);
#pragma unroll
                for (int mi = 0; mi < 4; ++mi)
#pragma unroll
                    for (int ni = 0; ni < 4; ++ni)
                        acc[mi][ni] = __builtin_amdgcn_mfma_f32_16x16x32_f16(ah[mi], bl[ni], acc[mi][ni], 0, 0, 0);
            }
        }

#pragma unroll
        for (int ni = 0; ni < 4; ++ni) {
            const int c = c0 + wave_n * 64 + ni * 16 + lane15;
            const float nrm = nc[c];
#pragma unroll
            for (int mi = 0; mi < 4; ++mi)
#pragma unroll
                for (int r = 0; r < 4; ++r) {
                    const float v = fmaf(-2.0f, acc[mi][ni][r], nrm);
                    if (v < minv[mi][r]) { minv[mi][r] = v; mini[mi][r] = c; }
                }
        }
    }

    __syncthreads();
    float* redv = (float*)smem;
    int*   redi = (int*)(smem + 16384);
#pragma unroll
    for (int mi = 0; mi < 4; ++mi)
#pragma unroll
        for (int r = 0; r < 4; ++r) {
            const int rl = wave_m * 64 + mi * 16 + quad * 4 + r;
            const int o = wave_n * 2048 + rl * 16 + lane15;
            redv[o] = minv[mi][r];
            redi[o] = mini[mi][r];
        }
    __syncthreads();
    if (tid < BMT) {
        float bv = __builtin_inff();
        int   bi = 0x7fffffff;
        for (int j = 0; j < 32; ++j) {
            const int o = (j >= 16 ? 2048 : 0) + tid * 16 + (j & 15);
            const float v = redv[o];
            const int   i = redi[o];
            if (v < bv || (v == bv && i < bi)) { bv = v; bi = i; }
        }
        fpart[(size_t)(row0 + tid) * SLICES + ns] = make_float2(bv, __int_as_float(bi));
    }
}

// Kernel 5b (slow path): merge slice partials for all tokens.
__global__ void vq_final_full_kernel(const float* __restrict__ z_e,
                                     const float* __restrict__ cb,
                                     const float2* __restrict__ fpart,
                                     float* __restrict__ out,
                                     float* __restrict__ accum) {
    __shared__ float wpart[4];
    const int wid  = threadIdx.x >> 6;
    const int lane = threadIdx.x & 63;
    const int tbase = blockIdx.x * 64 + wid * 16;
    float part = 0.0f;
#pragma unroll 1
    for (int t = 0; t < 16; ++t) {
        const int token = tbase + t;
        float bv = __builtin_inff();
        int   bi = 0x7fffffff;
#pragma unroll
        for (int s = 0; s < SLICES; ++s) {
            float2 p = fpart[(size_t)token * SLICES + s];
            const float v = p.x; const int i = __float_as_int(p.y);
            if (v < bv || (v == bv && i < bi)) { bv = v; bi = i; }
        }
        const int code = bi & (N_CODES - 1);
        const float4* zp = (const float4*)(z_e + (size_t)token * DIM);
        const float4* cp = (const float4*)(cb + (size_t)code * DIM);
        float4* op = (float4*)out + (size_t)token * (DIM / 4);
#pragma unroll
        for (int i = 0; i < 2; ++i) {
            const int e = lane + i * 64;
            float4 z = zp[e];
            float4 q = cp[e];
            op[e] = q;
            float dx = z.x - q.x, dy = z.y - q.y, dz = z.z - q.z, dw = z.w - q.w;
            part += dx * dx + dy * dy + dz * dz + dw * dw;
        }
        if (lane == 0) out[OUT_IDX + token] = (float)code;
    }
#pragma unroll
    for (int off = 32; off > 0; off >>= 1) part += __shfl_down(part, off);
    if (lane == 0) wpart[wid] = part;
    __syncthreads();
    if (threadIdx.x == 0) atomicAdd(accum, wpart[0] + wpart[1] + wpart[2] + wpart[3]);
}

// ---------------------------------------------------------------------------
// Kernel 6: finalize losses
__global__ void vq_finalize_kernel(const float* __restrict__ accum,
                                   float* __restrict__ out) {
    const float c = *accum * (1.0f / (float)(N_TOKENS * DIM));
    out[OUT_VQ]     = 0.25f * c;
    out[OUT_COMMIT] = c;
}

// ---------------------------------------------------------------------------
extern "C" void kernel_launch(void* const* d_in, const int* in_sizes, int n_in,
                              void* d_out, int out_size, void* d_ws, size_t ws_size,
                              hipStream_t stream) {
    const float* z_e = (const float*)d_in[0];
    const float* cb  = (const float*)d_in[1];
    float* out = (float*)d_out;

    _Float16*     cb_hi  = (_Float16*)((char*)d_ws + WS_CBHI);
    _Float16*     cb_lo  = (_Float16*)((char*)d_ws + WS_CBLO);
    float*        nc     = (float*)((char*)d_ws + WS_NC);
    float2*       normz  = (float2*)((char*)d_ws + WS_NORMZ);
    unsigned long long* fexact = (unsigned long long*)((char*)d_ws + WS_NORMZ); // alias (normz dead per-token at flag time)
    unsigned int* misc   = (unsigned int*)((char*)d_ws + WS_MISC);
    int*          list   = (int*)((char*)d_ws + WS_LIST);
    Part*         parts  = (Part*)((char*)d_ws + WS_PART);
    float2*       fpart  = (float2*)((char*)d_ws + WS_PART);   // slow path only
    _Float16*     ze_hi  = (_Float16*)((char*)d_ws + WS_ZEHI);
    _Float16*     ze_lo  = (_Float16*)((char*)d_ws + WS_ZELO);
    int*          flagcnt = (int*)&misc[2];
    float*        accum   = (float*)&misc[3];

    const bool fast = (ws_size >= (size_t)WS_NEED_FAST);  // call-invariant -> graph-safe

    hipLaunchKernelGGL(vq_init_kernel, dim3(1), dim3(64), 0, stream, misc);
    hipLaunchKernelGGL(vq_prep_cb_kernel, dim3(N_CODES / 4), dim3(256), 0, stream,
                       cb, cb_hi, cb_lo, nc, misc);
    if (fast) {
        hipLaunchKernelGGL(vq_prep_ze_kernel, dim3(N_TOKENS / 4), dim3(256), 0, stream,
                           z_e, ze_hi, ze_lo, normz);
        hipLaunchKernelGGL(vq_main_hi_kernel, dim3(N_TOKENS / BMT, SLICES), dim3(256), 0, stream,
                           ze_hi, cb_hi, nc, parts);
        hipLaunchKernelGGL(vq_merge_cert_kernel, dim3(N_TOKENS / 64), dim3(256), 0, stream,
                           z_e, cb, nc, parts, normz, fexact, misc, list, out, accum);
        hipLaunchKernelGGL(vq_exact_fine_kernel, dim3(CAP_FLAG / BMT, 32), dim3(256), 0, stream,
                           ze_hi, ze_lo, cb_hi, cb_lo, nc, list, flagcnt, fexact);
        hipLaunchKernelGGL(vq_final_flag_kernel, dim3(CAP_FLAG / 64), dim3(256), 0, stream,
                           z_e, cb, fexact, list, flagcnt, out, accum);
    } else {
        hipLaunchKernelGGL(vq_exact_full_kernel, dim3(N_TOKENS / BMT, SLICES), dim3(256), 0, stream,
                           z_e, cb_hi, cb_lo, nc, fpart);
        hipLaunchKernelGGL(vq_final_full_kernel, dim3(N_TOKENS / 64), dim3(256), 0, stream,
                           z_e, cb, fpart, out, accum);
    }
    hipLaunchKernelGGL(vq_finalize_kernel, dim3(1), dim3(1), 0, stream, accum, out);
}